// Round 11
// baseline (102.207 us; speedup 1.0000x reference)
//
#include <hip/hip_runtime.h>
#include <hip/hip_bf16.h>

// SEQ=512, BATCH=64, DIM=512, MAXLEN=512, E=655360
// out[b][u][s] = edge(b,u,s) ? exp(scale) / (T_e + 1e-10*(T-T_e)) : 0  (max cancels)
// scale[s,b,m] = sum_d M[s,b,d] * W[m,d]
//
// Single fused kernel, NO pre-convert pass:
//   block = (b, m-tile 64) x s=512; 8 waves, wave wv owns s-band wv*64..+63.
//   A = W f32 -> bf16 staged once into 64 KB LDS (swizzled, conflict-free).
//   B = M f32 DMA'd via global_load_lds, BK=16 steps (4 KB/step/wave), 3-slot
//   ring consumed in pairs (K=32), counted vmcnt(4), ZERO barriers in K-loop.
//   f32->bf16 conversion happens at fragment read (cvt_pk, hides under MFMA).

#define SEQ 512
#define BATCH 64
#define DIM 512
#define MAXLEN 512

typedef __attribute__((ext_vector_type(8))) __bf16 bf16x8;
typedef __attribute__((ext_vector_type(4))) float f32x4;

__device__ __forceinline__ unsigned cvt_pk(float lo, float hi) {
    unsigned r;
    asm("v_cvt_pk_bf16_f32 %0, %1, %2" : "=v"(r) : "v"(lo), "v"(hi));
    return r;
}

__device__ __forceinline__ void gload16(const void* g, void* l) {
    __builtin_amdgcn_global_load_lds(
        (const __attribute__((address_space(1))) void*)g,
        (__attribute__((address_space(3))) void*)l, 16, 0, 0);
}

// ---------------- edge bitmap scatter ----------------
__global__ __launch_bounds__(256) void edge_scatter(const int* __restrict__ eb,
                                                    const int* __restrict__ eu,
                                                    const int* __restrict__ ev,
                                                    unsigned int* __restrict__ bits,
                                                    int E) {
    int i = blockIdx.x * 256 + threadIdx.x;
    if (i < E) {
        int b = eb[i], u = eu[i], v = ev[i];
        atomicOr(&bits[(b * MAXLEN + u) * 16 + (v >> 5)], 1u << (v & 31));
    }
}

// ---------------- fused GEMM + softmax + edge renorm ----------------
__global__ __launch_bounds__(512, 1) void fused_attn(
    const float* __restrict__ Mg,
    const float* __restrict__ Wg,
    const unsigned int* __restrict__ bitsG,
    float* __restrict__ out) {
    // LDS (160 KiB exactly):
    //   [0,65536):      A bf16 64 rows x 1024 B; LDS chunk c of row r = src chunk c^(r&7)
    //   [65536,163840): B f32, 3 slots x 8 waves x (64 rows x 64 B = K16);
    //                   LDS chunk c of row r = src chunk c^((r>>1)&3)
    //   epilogue overlays: red float2[64][8] at +65536; stg [16][516] f32 at 0
    __shared__ __align__(16) char lds[163840];

    const int g = blockIdx.x;
    const int work = (g & 7) * 64 + (g >> 3);   // bijective [0,512): same-b -> one XCD
    const int b  = work >> 3;
    const int m0 = (work & 7) * 64;

    const int t = threadIdx.x, lane = t & 63, wv = t >> 6;
    const int lg = lane >> 4, lc = lane & 15;

    // ---- B DMA source (swizzle folded into per-lane source chunk) ----
    // step s covers f32 k-range [s*16, s*16+16) = 64 B per s-row
    const int rr = lane >> 2;                          // row-sub within 16-row group
    const int cs = (lane & 3) ^ ((lane >> 3) & 3);     // src chunk for own LDS slot
    const char* const bsrc =
        (const char*)Mg + ((size_t)(wv * 64 + rr) * BATCH + b) * 2048 + cs * 16;
    char* const band = lds + 65536 + wv * 4096;        // + slot*32768 + q*1024

    // prologue: issue steps 0,1,2 (12 DMA insts per wave)
#pragma unroll
    for (int s = 0; s < 3; ++s)
#pragma unroll
        for (int q = 0; q < 4; ++q)
            gload16(bsrc + ((size_t)q << 21) + s * 64, band + s * 32768 + q * 1024);

    // ---- stage A tile: W f32 (64 x 512) -> bf16 LDS resident, swizzled ----
    {
        const char* wb = (const char*)Wg + (size_t)m0 * 2048;
        const int r = t >> 3;                  // 0..63
#pragma unroll
        for (int i = 0; i < 8; ++i) {
            int ch = (t & 7) + 8 * i;          // LDS 16B-chunk; 8 lanes span 8 quads
            int cg = ch ^ (r & 7);             // source bf16-chunk -> f32 bytes cg*32
            float4 x = *(const float4*)(wb + (size_t)r * 2048 + cg * 32);
            float4 y = *(const float4*)(wb + (size_t)r * 2048 + cg * 32 + 16);
            uint4 o;
            o.x = cvt_pk(x.x, x.y); o.y = cvt_pk(x.z, x.w);
            o.z = cvt_pk(y.x, y.y); o.w = cvt_pk(y.z, y.w);
            *(uint4*)(lds + r * 1024 + ch * 16) = o;
        }
    }
    __syncthreads();   // A visible to all waves

    f32x4 acc[4][4] = {};
    const int swB = (lc >> 1) & 3;
    const int swA = lc & 7;
    const int c0  = (lg & 1) * 2;              // B chunk base within 64B slice
    const int selB = lg & 2;                   // lg>=2 -> odd slot (second K16 half)

#pragma unroll
    for (int tp = 0; tp < 16; ++tp) {          // pair tp = steps 2tp, 2tp+1 (K=32)
        if (tp < 15) asm volatile("s_waitcnt vmcnt(4)" ::: "memory");
        else         asm volatile("s_waitcnt vmcnt(0)" ::: "memory");

        const int sA = ((2 * tp) % 3) * 32768;       // slot holding k [tp*32, +16)
        const int sB = ((2 * tp + 1) % 3) * 32768;   // slot holding k [tp*32+16, +16)

        bf16x8 af[4], bfr[4];
#pragma unroll
        for (int j = 0; j < 4; ++j) {
            const char* base = lds + 65536 + (selB ? sB : sA) + wv * 4096
                             + (j * 16 + lc) * 64;
            f32x4 x = *(const f32x4*)(base + ((c0 ^ swB) * 16));
            f32x4 y = *(const f32x4*)(base + (((c0 + 1) ^ swB) * 16));
            uint4 pk;
            pk.x = cvt_pk(x[0], x[1]); pk.y = cvt_pk(x[2], x[3]);
            pk.z = cvt_pk(y[0], y[1]); pk.w = cvt_pk(y[2], y[3]);
            bfr[j] = __builtin_bit_cast(bf16x8, pk);
        }
#pragma unroll
        for (int i = 0; i < 4; ++i)
            af[i] = *(const bf16x8*)(lds + (i * 16 + lc) * 1024
                                     + (((4 * tp + lg) ^ swA) * 16));

        __builtin_amdgcn_s_setprio(1);
#pragma unroll
        for (int i = 0; i < 4; ++i)
#pragma unroll
            for (int j = 0; j < 4; ++j)
                acc[i][j] = __builtin_amdgcn_mfma_f32_16x16x32_bf16(af[i], bfr[j], acc[i][j], 0, 0, 0);
        __builtin_amdgcn_s_setprio(0);

        __builtin_amdgcn_sched_barrier(0);   // DMA reissues stay after this pair's reads
        if (2 * tp + 3 < 32) {               // -> slot (2tp)%3
#pragma unroll
            for (int q = 0; q < 4; ++q)
                gload16(bsrc + ((size_t)q << 21) + (2 * tp + 3) * 64,
                        band + sA + q * 1024);
        }
        if (2 * tp + 4 < 32) {               // -> slot (2tp+1)%3
#pragma unroll
            for (int q = 0; q < 4; ++q)
                gload16(bsrc + ((size_t)q << 21) + (2 * tp + 4) * 64,
                        band + sB + q * 1024);
        }
    }

    __syncthreads();   // all waves done with B region before red overlay

    float2* const red = (float2*)(lds + 65536);
    // ---- epilogue pass 1: exp + per-wave (T,Te) partials ----
#pragma unroll
    for (int i = 0; i < 4; ++i) {
#pragma unroll
        for (int r = 0; r < 4; ++r) {
            const int m = i * 16 + lg * 4 + r;
            const uint2 wbt = *(const uint2*)(bitsG + (size_t)(b * MAXLEN + m0 + m) * 16 + wv * 2);
            float T = 0.f, Te = 0.f;
#pragma unroll
            for (int j = 0; j < 4; ++j) {
                float e = __expf(acc[i][j][r]);
                acc[i][j][r] = e;
                unsigned word = (j & 2) ? wbt.y : wbt.x;
                float bit = (float)((word >> ((j & 1) * 16 + lc)) & 1u);
                T += e; Te += e * bit;
            }
#pragma unroll
            for (int off = 1; off < 16; off <<= 1) {
                T  += __shfl_xor(T, off);
                Te += __shfl_xor(Te, off);
            }
            if (lc == 0) red[m * 8 + wv] = make_float2(T, Te);
        }
    }
    __syncthreads();

    // ---- epilogue pass 2: masked scale -> LDS transpose -> coalesced stores ----
    float* const stg = (float*)lds;
    for (int i = 0; i < 4; ++i) {
        float inv[4];
        uint2 wbt2[4];
#pragma unroll
        for (int r = 0; r < 4; ++r) {
            const int m = i * 16 + lg * 4 + r;
            float T = 0.f, Te = 0.f;
#pragma unroll
            for (int q = 0; q < 8; ++q) {
                float2 p = red[m * 8 + q];
                T += p.x; Te += p.y;
            }
            inv[r] = 1.0f / (Te + 1e-10f * (T - Te));
            wbt2[r] = *(const uint2*)(bitsG + (size_t)(b * MAXLEN + m0 + m) * 16 + wv * 2);
        }
#pragma unroll
        for (int r = 0; r < 4; ++r) {
#pragma unroll
            for (int j = 0; j < 4; ++j) {
                unsigned word = (j & 2) ? wbt2[r].y : wbt2[r].x;
                unsigned bit = (word >> ((j & 1) * 16 + lc)) & 1u;
                stg[(lg * 4 + r) * 516 + wv * 64 + j * 16 + lc] =
                    bit ? acc[i][j][r] * inv[r] : 0.0f;
            }
        }
        __syncthreads();
#pragma unroll
        for (int it = 0; it < 4; ++it) {
            int f = it * 512 + t;
            int ml = f >> 7;
            int s4 = (f & 127) * 4;
            float4 v = *(const float4*)(stg + ml * 516 + s4);
            *(float4*)(out + ((size_t)(b * MAXLEN + m0 + i * 16 + ml)) * SEQ + s4) = v;
        }
        __syncthreads();
    }
}

// ================= launch =================

extern "C" void kernel_launch(void* const* d_in, const int* in_sizes, int n_in,
                              void* d_out, int out_size, void* d_ws, size_t ws_size,
                              hipStream_t stream) {
    const float* Mg = (const float*)d_in[0];
    const float* Wg = (const float*)d_in[1];
    // d_in[2] = lengths (unused by reference)
    const int* eb = (const int*)d_in[3];
    const int* eu = (const int*)d_in[4];
    const int* ev = (const int*)d_in[5];
    const int E = in_sizes[3];

    float* out = (float*)d_out;
    unsigned int* bits = (unsigned int*)d_ws;   // 32768 rows * 16 words = 2 MB

    (void)hipMemsetAsync(bits, 0, (size_t)BATCH * MAXLEN * 16 * sizeof(unsigned int), stream);
    edge_scatter<<<(E + 255) / 256, 256, 0, stream>>>(eb, eu, ev, bits, E);
    fused_attn<<<512, 512, 0, stream>>>(Mg, Wg, bits, out);
}